// Round 19
// baseline (86.426 us; speedup 1.0000x reference)
//
#include <hip/hip_runtime.h>
#include <math.h>

#define NEXP 8
#define DIN 128
#define NTOK (16 * 4096)           // 65536
// wave = 16 tokens, block = 4 waves = 64 tokens, grid = 1024

#define LPITCH 136                 // LDS pitch (floats) for [16 tok][128 outc] tile
#define LDS_PER_WAVE (16 * LPITCH) // 2176 floats = 8704 B
#define SMEM_BYTES (4 * LDS_PER_WAVE * 4)   // 34816 B

typedef float f32x4 __attribute__((ext_vector_type(4)));
typedef unsigned int u32;
typedef u32 u32x2 __attribute__((ext_vector_type(2)));
typedef u32 u32x4 __attribute__((ext_vector_type(4)));
typedef short short8 __attribute__((ext_vector_type(8)));

__device__ __forceinline__ u32 pk2(float lo, float hi) {
    // two bf16 (round-half-up): lo -> low 16 bits, hi -> high 16 bits
    return ((__float_as_uint(hi) + 0x8000u) & 0xffff0000u) |
           ((__float_as_uint(lo) + 0x8000u) >> 16);
}

// tanh-form GELU: y * sigmoid(1.5957691216*(y + 0.044715 y^3))
// max |diff vs exact erf-GELU| ~3e-3 absolute -> absorbed by bf16 threshold.
__device__ __forceinline__ float gelu_t(float y) {
    float t  = y * y;
    float u2 = -1.5957691216057308f * y * __builtin_fmaf(0.044715f, t, 1.0f);
    return y / (1.0f + __expf(u2));
}

// ---- pack w1/w2 into MFMA fragment order (bf16) in d_ws (verified r13-r18) ----
// P1 (8192 u32): GEMM1 A-frags: entry (nb*4+kb)*64+l, reg c: pair
//   (w1[nb][ch][i], w1[nb][ch+1][i]), ch = kb*32 + (l>>4)*8 + 2c, i = l&15.
// P2 (8192 u32): GEMM2 A-frags (w2), u32x4 per lane covering cb pair:
//   P2[((e*4+cp)*64+l)*4 + c2], s=c2>>1, c=c2&1: pair
//   (w2[e][i0][outc], w2[e][i0+1][outc]), i0=(l>>4)*4+2c, outc=(2cp+s)*16+(l&15).
__global__ void pack_weights_kernel(const float* __restrict__ w1,
                                    const float* __restrict__ w2,
                                    u32* __restrict__ P1u,
                                    u32* __restrict__ P2u) {
    int idx = blockIdx.x * 256 + threadIdx.x;       // 0 .. 16383
    if (idx < 8192) {
        int c     = idx & 3;
        int entry = idx >> 2;
        int l     = entry & 63;
        int nbkb  = entry >> 6;            // 0..31
        int nb = nbkb >> 2, kb = nbkb & 3;
        int qq = l >> 4, row = l & 15;
        int ch = kb * 32 + qq * 8 + 2 * c;
        const float* s = w1 + nb * 2048 + ch * 16 + row;
        P1u[idx] = pk2(s[0], s[16]);
    } else {
        int j     = idx - 8192;            // 0 .. 8191
        int c2    = j & 3;
        int entry = j >> 2;                // 0 .. 2047
        int l     = entry & 63;
        int ecp   = entry >> 6;            // 0..31
        int e = ecp >> 2, cp = ecp & 3;
        int s = c2 >> 1, c = c2 & 1;
        int i0 = (l >> 4) * 4 + 2 * c;
        int outc = (2 * cp + s) * 16 + (l & 15);
        const float* src = w2 + e * 2048 + i0 * 128 + outc;
        P2u[j] = pk2(src[0], src[128]);
    }
}

__global__ __launch_bounds__(256, 1) __attribute__((amdgpu_num_vgpr(128)))
void moe_mfma_kernel(
    const float* __restrict__ x,
    const float* __restrict__ rw,
    const unsigned short* __restrict__ P1,   // packed w1 frags
    const u32* __restrict__ P2,              // packed w2 frags (u32x4/lane)
    float* __restrict__ out_agg,
    float* __restrict__ out_exp)
{
    extern __shared__ float lds[];

    const int tid  = threadIdx.x;
    const int wave = tid >> 6;
    const int lane = tid & 63;
    const int q    = lane >> 4;
    const int n16  = lane & 15;
    const int wtok = blockIdx.x * 64 + wave * 16;

    float* Lw = lds + wave * LDS_PER_WAVE;   // wave-private [16][LPITCH] tile

    const size_t tok = (size_t)(wtok + n16);

    // ---- early loads: x fragments + routing weights (overlap L2/HBM latency) ----
    short8 b1[4];
    f32x4 rwv0, rwv1;                        // rw[tok][0..3], rw[tok][4..7]
    {
        const float* xb = x + tok * DIN + q * 8;
        const float* rp = rw + tok * NEXP;
        rwv0 = *(const f32x4*)(rp);
        rwv1 = *(const f32x4*)(rp + 4);
#pragma unroll
        for (int kb = 0; kb < 4; ++kb) {
            f32x4 lo = *(const f32x4*)(xb + kb * 32);
            f32x4 hi = *(const f32x4*)(xb + kb * 32 + 4);
            u32x4 u;
            u.x = pk2(lo.x, lo.y); u.y = pk2(lo.z, lo.w);
            u.z = pk2(hi.x, hi.y); u.w = pk2(hi.z, hi.w);
            b1[kb] = __builtin_bit_cast(short8, u);
        }
    }

    // ---- GEMM1 (swapped): c1[e][r] = y[tok=n16][e][i=4q+r] (verified) ----
    const short8* P1f = (const short8*)P1;
    f32x4 c1[8];
#pragma unroll
    for (int nb = 0; nb < 8; ++nb) {
        f32x4 a = {0.f, 0.f, 0.f, 0.f};
#pragma unroll
        for (int kb = 0; kb < 4; ++kb) {
            short8 af = P1f[(nb * 4 + kb) * 64 + lane];
            a = __builtin_amdgcn_mfma_f32_16x16x32_bf16(af, b1[kb], a, 0, 0, 0);
        }
        c1[nb] = a;
    }

    // ---- GELU (tanh form) + bf16 pack: pa[e] = (gy[4q+0,1], gy[4q+2,3]) ----
    u32x2 pa[8];
#pragma unroll
    for (int e = 0; e < 8; ++e) {
        float g0 = gelu_t(c1[e][0]);
        float g1 = gelu_t(c1[e][1]);
        float g2 = gelu_t(c1[e][2]);
        float g3 = gelu_t(c1[e][3]);
        pa[e].x = pk2(g0, g1);
        pa[e].y = pk2(g2, g3);
    }

    // ---- GEMM2 swapped: o = mfma(w2frag, gyfrag) -> C2s[outc=cb*16+4q+r][tok=n16]
    //      MFMA out -> wave-private LDS (token-major) -> contiguous global stores
    const u32x4* P2f = (const u32x4*)P2;
    f32x4 aggs[8];
#pragma unroll
    for (int cb = 0; cb < 8; ++cb) aggs[cb] = (f32x4){0.f, 0.f, 0.f, 0.f};

    const f32x4 z = {0.f, 0.f, 0.f, 0.f};
    // drain mapping: instr k covers tokens 2k, 2k+1 (2 x 512 B segments)
    const int rtok = (lane >> 5);            // 0/1: which of the 2 tokens
    const int rc   = (lane & 31) * 4;        // 0..124: outc quad

#pragma unroll
    for (int e = 0; e < 8; ++e) {
        u32x4 au = {pa[e].x, pa[e].y, pa[e].x, pa[e].y};    // hi: don't-care (x0)
        short8 gfrag = __builtin_bit_cast(short8, au);
        const float rwe = (e < 4) ? rwv0[e & 3] : rwv1[e & 3];  // static per unroll

#pragma unroll
        for (int cp = 0; cp < 4; ++cp) {
            u32x4 W = P2f[(e * 4 + cp) * 64 + lane];
            // cb = 2cp
            {
                u32x4 wu = {W.x, W.y, 0u, 0u};              // hi rows = zero
                short8 wf = __builtin_bit_cast(short8, wu);
                f32x4 o = __builtin_amdgcn_mfma_f32_16x16x32_bf16(wf, gfrag, z, 0, 0, 0);
                *(f32x4*)(Lw + n16 * LPITCH + (2 * cp) * 16 + 4 * q) = o;
                aggs[2 * cp] += rwe * o;
            }
            // cb = 2cp+1
            {
                u32x4 wu = {W.z, W.w, 0u, 0u};
                short8 wf = __builtin_bit_cast(short8, wu);
                f32x4 o = __builtin_amdgcn_mfma_f32_16x16x32_bf16(wf, gfrag, z, 0, 0, 0);
                *(f32x4*)(Lw + n16 * LPITCH + (2 * cp + 1) * 16 + 4 * q) = o;
                aggs[2 * cp + 1] += rwe * o;
            }
        }

        // drain expert e: 8 instrs, each storing 2 contiguous 512 B token-rows
        float* oe = out_exp + (size_t)wtok * (NEXP * DIN) + e * DIN;
#pragma unroll
        for (int k = 0; k < 8; ++k) {
            const int t2 = 2 * k + rtok;
            f32x4 v = *(const f32x4*)(Lw + t2 * LPITCH + rc);
            *(f32x4*)(oe + (size_t)t2 * (NEXP * DIN) + rc) = v;
        }
    }

    // ---- agg: same LDS transpose -> contiguous out_agg rows ----
#pragma unroll
    for (int cb = 0; cb < 8; ++cb)
        *(f32x4*)(Lw + n16 * LPITCH + cb * 16 + 4 * q) = aggs[cb];

    float* oa = out_agg + (size_t)wtok * DIN;
#pragma unroll
    for (int k = 0; k < 8; ++k) {
        const int t2 = 2 * k + rtok;
        f32x4 v = *(const f32x4*)(Lw + t2 * LPITCH + rc);
        *(f32x4*)(oa + (size_t)t2 * DIN + rc) = v;
    }
}

extern "C" void kernel_launch(void* const* d_in, const int* in_sizes, int n_in,
                              void* d_out, int out_size, void* d_ws, size_t ws_size,
                              hipStream_t stream) {
    const float* x  = (const float*)d_in[0];
    const float* rw = (const float*)d_in[1];
    const float* w1 = (const float*)d_in[2];
    const float* w2 = (const float*)d_in[3];

    float* out_agg = (float*)d_out;                  // [NTOK][128]
    float* out_exp = out_agg + (size_t)NTOK * DIN;   // [NTOK][8][128]
    u32* P1u = (u32*)d_ws;                           // 32 KB w1 frags
    u32* P2u = P1u + 8192;                           // 32 KB w2 frags

    pack_weights_kernel<<<dim3(64), dim3(256), 0, stream>>>(w1, w2, P1u, P2u);

    dim3 grid(NTOK / 64);   // 1024
    dim3 block(256);
    moe_mfma_kernel<<<grid, block, SMEM_BYTES, stream>>>(
        x, rw, (const unsigned short*)P1u, P2u, out_agg, out_exp);
}

// Round 20
// 79.472 us; speedup vs baseline: 1.0875x; 1.0875x over previous
//
#include <hip/hip_runtime.h>
#include <math.h>

#define NEXP 8
#define DIN 128
#define NTOK (16 * 4096)           // 65536
// wave = 16 tokens, block = 4 waves = 64 tokens, grid = 1024

#define PPITCH 260                 // LDS pitch (floats): 256 (expert pair) + 4 pad
#define LDS_PER_WAVE (16 * PPITCH) // 4160 floats = 16640 B
#define SMEM_BYTES (4 * LDS_PER_WAVE * 4)   // 66560 B -> 2 blocks/CU

typedef float f32x4 __attribute__((ext_vector_type(4)));
typedef unsigned int u32;
typedef u32 u32x2 __attribute__((ext_vector_type(2)));
typedef u32 u32x4 __attribute__((ext_vector_type(4)));
typedef short short8 __attribute__((ext_vector_type(8)));

__device__ __forceinline__ u32 pk2(float lo, float hi) {
    // two bf16 (round-half-up): lo -> low 16 bits, hi -> high 16 bits
    return ((__float_as_uint(hi) + 0x8000u) & 0xffff0000u) |
           ((__float_as_uint(lo) + 0x8000u) >> 16);
}

// ---- pack w1/w2 into MFMA fragment order (bf16) in d_ws (verified r13-r19) ----
// P1 (8192 u32): GEMM1 A-frags: entry (nb*4+kb)*64+l, reg c: pair
//   (w1[nb][ch][i], w1[nb][ch+1][i]), ch = kb*32 + (l>>4)*8 + 2c, i = l&15.
// P2 (8192 u32): GEMM2 A-frags (w2), u32x4 per lane covering cb pair:
//   P2[((e*4+cp)*64+l)*4 + c2], s=c2>>1, c=c2&1: pair
//   (w2[e][i0][outc], w2[e][i0+1][outc]), i0=(l>>4)*4+2c, outc=(2cp+s)*16+(l&15).
__global__ void pack_weights_kernel(const float* __restrict__ w1,
                                    const float* __restrict__ w2,
                                    u32* __restrict__ P1u,
                                    u32* __restrict__ P2u) {
    int idx = blockIdx.x * 256 + threadIdx.x;       // 0 .. 16383
    if (idx < 8192) {
        int c     = idx & 3;
        int entry = idx >> 2;
        int l     = entry & 63;
        int nbkb  = entry >> 6;            // 0..31
        int nb = nbkb >> 2, kb = nbkb & 3;
        int qq = l >> 4, row = l & 15;
        int ch = kb * 32 + qq * 8 + 2 * c;
        const float* s = w1 + nb * 2048 + ch * 16 + row;
        P1u[idx] = pk2(s[0], s[16]);
    } else {
        int j     = idx - 8192;            // 0 .. 8191
        int c2    = j & 3;
        int entry = j >> 2;                // 0 .. 2047
        int l     = entry & 63;
        int ecp   = entry >> 6;            // 0..31
        int e = ecp >> 2, cp = ecp & 3;
        int s = c2 >> 1, c = c2 & 1;
        int i0 = (l >> 4) * 4 + 2 * c;
        int outc = (2 * cp + s) * 16 + (l & 15);
        const float* src = w2 + e * 2048 + i0 * 128 + outc;
        P2u[j] = pk2(src[0], src[128]);
    }
}

__global__ __launch_bounds__(256, 1) __attribute__((amdgpu_num_vgpr(128)))
void moe_mfma_kernel(
    const float* __restrict__ x,
    const float* __restrict__ rw,
    const unsigned short* __restrict__ P1,   // packed w1 frags
    const u32* __restrict__ P2,              // packed w2 frags (u32x4/lane)
    float* __restrict__ out_agg,
    float* __restrict__ out_exp)
{
    extern __shared__ float lds[];

    const int tid  = threadIdx.x;
    const int wave = tid >> 6;
    const int lane = tid & 63;
    const int q    = lane >> 4;
    const int n16  = lane & 15;
    const int wtok = blockIdx.x * 64 + wave * 16;

    float* Lw = lds + wave * LDS_PER_WAVE;   // wave-private [16][PPITCH] pair tile

    // ---- B1 frags: position (q,j) of kb-block = x[wtok+n16][kb*32+q*8+j] ----
    short8 b1[4];
    {
        const float* xb = x + (size_t)(wtok + n16) * DIN + q * 8;
#pragma unroll
        for (int kb = 0; kb < 4; ++kb) {
            f32x4 lo = *(const f32x4*)(xb + kb * 32);
            f32x4 hi = *(const f32x4*)(xb + kb * 32 + 4);
            u32x4 u;
            u.x = pk2(lo.x, lo.y); u.y = pk2(lo.z, lo.w);
            u.z = pk2(hi.x, hi.y); u.w = pk2(hi.z, hi.w);
            b1[kb] = __builtin_bit_cast(short8, u);
        }
    }

    // ---- GEMM1 (swapped): c1[e][r] = y[tok=n16][e][i=4q+r] (verified) ----
    const short8* P1f = (const short8*)P1;
    f32x4 c1[8];
#pragma unroll
    for (int nb = 0; nb < 8; ++nb) {
        f32x4 a = {0.f, 0.f, 0.f, 0.f};
#pragma unroll
        for (int kb = 0; kb < 4; ++kb) {
            short8 af = P1f[(nb * 4 + kb) * 64 + lane];
            a = __builtin_amdgcn_mfma_f32_16x16x32_bf16(af, b1[kb], a, 0, 0, 0);
        }
        c1[nb] = a;
    }

    // ---- exact GELU + bf16 pack: pa[e] = (gy[4q+0,1], gy[4q+2,3]) for tok n16 ----
    u32x2 pa[8];
#pragma unroll
    for (int e = 0; e < 8; ++e) {
        float g0 = c1[e][0], g1 = c1[e][1], g2 = c1[e][2], g3 = c1[e][3];
        g0 = 0.5f * g0 * (1.f + erff(g0 * 0.70710678118654752f));
        g1 = 0.5f * g1 * (1.f + erff(g1 * 0.70710678118654752f));
        g2 = 0.5f * g2 * (1.f + erff(g2 * 0.70710678118654752f));
        g3 = 0.5f * g3 * (1.f + erff(g3 * 0.70710678118654752f));
        pa[e].x = pk2(g0, g1);
        pa[e].y = pk2(g2, g3);
    }

    // ---- GEMM2 swapped, expert-PAIR tiles: compute pair -> drain pair ----
    // o = mfma(w2frag, gyfrag) -> C2s[outc=cb*16+4q+r][tok=n16] -> LDS
    // [tok][hf*128 + outc]; drain: 16 instrs, each ONE contiguous 1024 B
    // token-row (experts 2ep,2ep+1 adjacent in out_exp).
    const u32x4* P2f = (const u32x4*)P2;
    f32x4 aggs[8];
#pragma unroll
    for (int cb = 0; cb < 8; ++cb) aggs[cb] = (f32x4){0.f, 0.f, 0.f, 0.f};

    const size_t tok = (size_t)(wtok + n16);
    const float* rwp = rw + tok * NEXP;
    const f32x4 z = {0.f, 0.f, 0.f, 0.f};
    float* oexp = out_exp + (size_t)wtok * (NEXP * DIN);

#pragma unroll
    for (int ep = 0; ep < 4; ++ep) {
#pragma unroll
        for (int hf = 0; hf < 2; ++hf) {
            const int e = 2 * ep + hf;
            u32x4 au = {pa[e].x, pa[e].y, pa[e].x, pa[e].y};   // hi: don't-care
            short8 gfrag = __builtin_bit_cast(short8, au);
            const float rwe = rwp[e];
#pragma unroll
            for (int cp = 0; cp < 4; ++cp) {
                u32x4 W = P2f[(e * 4 + cp) * 64 + lane];
                {
                    u32x4 wu = {W.x, W.y, 0u, 0u};             // hi rows = zero
                    short8 wf = __builtin_bit_cast(short8, wu);
                    f32x4 o = __builtin_amdgcn_mfma_f32_16x16x32_bf16(wf, gfrag, z, 0, 0, 0);
                    *(f32x4*)(Lw + n16 * PPITCH + hf * 128 + (2 * cp) * 16 + 4 * q) = o;
                    aggs[2 * cp] += rwe * o;
                }
                {
                    u32x4 wu = {W.z, W.w, 0u, 0u};
                    short8 wf = __builtin_bit_cast(short8, wu);
                    f32x4 o = __builtin_amdgcn_mfma_f32_16x16x32_bf16(wf, gfrag, z, 0, 0, 0);
                    *(f32x4*)(Lw + n16 * PPITCH + hf * 128 + (2 * cp + 1) * 16 + 4 * q) = o;
                    aggs[2 * cp + 1] += rwe * o;
                }
            }
        }

        // drain pair ep: 16 instrs, each storing one contiguous 1 KB token-row
#pragma unroll
        for (int k = 0; k < 16; ++k) {
            f32x4 v = *(const f32x4*)(Lw + k * PPITCH + lane * 4);
            *(f32x4*)(oexp + (size_t)k * (NEXP * DIN) + ep * 256 + lane * 4) = v;
        }
    }

    // ---- agg: LDS transpose -> out_agg; 2 adjacent 512 B rows = 1 KB/instr ----
#pragma unroll
    for (int cb = 0; cb < 8; ++cb)
        *(f32x4*)(Lw + n16 * PPITCH + cb * 16 + 4 * q) = aggs[cb];

    const int rtok = lane >> 5;              // 0/1: which of the 2 tokens
    const int rc   = (lane & 31) * 4;        // 0..124: outc quad
    float* oa = out_agg + (size_t)wtok * DIN;
#pragma unroll
    for (int k = 0; k < 8; ++k) {
        const int t2 = 2 * k + rtok;
        f32x4 v = *(const f32x4*)(Lw + t2 * PPITCH + rc);
        *(f32x4*)(oa + (size_t)t2 * DIN + rc) = v;
    }
}

extern "C" void kernel_launch(void* const* d_in, const int* in_sizes, int n_in,
                              void* d_out, int out_size, void* d_ws, size_t ws_size,
                              hipStream_t stream) {
    const float* x  = (const float*)d_in[0];
    const float* rw = (const float*)d_in[1];
    const float* w1 = (const float*)d_in[2];
    const float* w2 = (const float*)d_in[3];

    float* out_agg = (float*)d_out;                  // [NTOK][128]
    float* out_exp = out_agg + (size_t)NTOK * DIN;   // [NTOK][8][128]
    u32* P1u = (u32*)d_ws;                           // 32 KB w1 frags
    u32* P2u = P1u + 8192;                           // 32 KB w2 frags

    pack_weights_kernel<<<dim3(64), dim3(256), 0, stream>>>(w1, w2, P1u, P2u);

    dim3 grid(NTOK / 64);   // 1024
    dim3 block(256);
    moe_mfma_kernel<<<grid, block, SMEM_BYTES, stream>>>(
        x, rw, (const unsigned short*)P1u, P2u, out_agg, out_exp);
}